// Round 5
// baseline (474.315 us; speedup 1.0000x reference)
//
#include <hip/hip_runtime.h>
#include <hip/hip_bf16.h>

// B=32, C=256, H=36, W=64, n=4096.  P = H*W = 2304.  NCOL = B*C = 8192.
#define P_HW   2304
#define NG     4096
#define NCOL   8192
#define KDIM   P_HW

typedef __bf16 bf16x8 __attribute__((ext_vector_type(8)));
typedef float  f32x4  __attribute__((ext_vector_type(4)));

__device__ __forceinline__ unsigned short f2bf(float f) {
    union { float f; unsigned int u; } x; x.f = f;
    unsigned int r = x.u + 0x7FFFu + ((x.u >> 16) & 1u);   // RNE
    return (unsigned short)(r >> 16);
}

// ---------------------------------------------------------------------------
// Fused prep: [0,9216) cast feat->bf16 | [9216,13312) gaussian masks |
//             [13312,13376) zero out.  One dispatch, all independent.
// ---------------------------------------------------------------------------
__global__ __launch_bounds__(256) void prep_kernel(
    const float* __restrict__ feat,
    const float* __restrict__ mu,
    const float* __restrict__ logsx,
    const float* __restrict__ logsy,
    const float* __restrict__ rho,
    unsigned short* __restrict__ F,
    unsigned short* __restrict__ G,
    float* __restrict__ out) {
    const int bid = blockIdx.x;
    const int tid = threadIdx.x;
    if (bid < 9216) {
        // cast feat fp32 -> bf16, [B*C][P], 8 elems/thread
        const size_t i = ((size_t)bid * 256 + tid) * 8;
        const float4 v0 = *(const float4*)(feat + i);
        const float4 v1 = *(const float4*)(feat + i + 4);
        union { unsigned short s[8]; uint4 q; } o;
        o.s[0] = f2bf(v0.x); o.s[1] = f2bf(v0.y); o.s[2] = f2bf(v0.z); o.s[3] = f2bf(v0.w);
        o.s[4] = f2bf(v1.x); o.s[5] = f2bf(v1.y); o.s[6] = f2bf(v1.z); o.s[7] = f2bf(v1.w);
        *(uint4*)(F + i) = o.q;
    } else if (bid < 13312) {
        const int n = bid - 9216;
        const float mux = mu[2 * n], muy = mu[2 * n + 1];
        const float sx = __expf(logsx[n]) + 1e-6f;
        const float sy = __expf(logsy[n]) + 1e-6f;
        const float r  = tanhf(rho[n]);
        const float inv_den = 1.0f / (2.0f * (1.0f - r * r + 1e-6f));
        const float isx = 1.0f / sx, isy = 1.0f / sy;
        for (int base = tid * 8; base < P_HW; base += 2048) {
            const int h = base >> 6, w0 = base & 63;      // W = 64
            const float Y  = -1.0f + (float)h * (2.0f / 35.0f);
            const float yc = (Y - muy) * isy;
            union { unsigned short s[8]; uint4 q; } o;
#pragma unroll
            for (int j = 0; j < 8; ++j) {
                const float X  = -1.0f + (float)(w0 + j) * (2.0f / 63.0f);
                const float xc = (X - mux) * isx;
                const float A  = xc * xc + yc * yc - 2.0f * r * xc * yc;
                o.s[j] = f2bf(__expf(-A * inv_den));
            }
            *(uint4*)&G[(size_t)n * P_HW + base] = o.q;
        }
    } else {
        // zero out: 64 blocks * 256 threads * 8 floats = 131072 = 32*4096
        const size_t i = ((size_t)(bid - 13312) * 256 + tid) * 8;
        const float4 z = {0.f, 0.f, 0.f, 0.f};
        *(float4*)(out + i)     = z;
        *(float4*)(out + i + 4) = z;
    }
}

// ---------------------------------------------------------------------------
// GEMM: 128x128 tile, BK=64. B(F) staged in LDS via global_load_lds(16B) with
// XOR swizzle (conflict-free); A(G) fragments read DIRECTLY from global —
// halves LDS read/write traffic (the co-binding pipe at R4: ~92us of b128
// reads vs 62us MFMA floor). XCD-aware block swizzle puts all resident blocks
// of one XCD on the same 590KB G panel so A-frag reads are L2-hot.
// ---------------------------------------------------------------------------
__device__ __forceinline__ void async16(const void* g, void* l) {
    __builtin_amdgcn_global_load_lds(
        (__attribute__((address_space(1))) void*)(unsigned long long)g,
        (__attribute__((address_space(3))) void*)(unsigned int)(unsigned long long)l,
        16, 0, 0);
}

__global__ __launch_bounds__(256) void gemm_fused(
    const unsigned short* __restrict__ G,   // [NG][K] bf16
    const unsigned short* __restrict__ F,   // [NCOL][K] bf16
    const float* __restrict__ weight,       // [NG][256] fp32
    float* __restrict__ out)                // [32][NG] fp32 (pre-zeroed)
{
    __shared__ __align__(16) unsigned short ldsB[128 * 64];   // 16 KB

    const int tid  = threadIdx.x;
    const int lane = tid & 63;
    const int wave = tid >> 6;
    const int waveM = wave >> 1, waveN = wave & 1;
    const int quad = lane >> 4, m = lane & 15;

    // XCD swizzle: bid%8 ~ XCD (round-robin heuristic). Give each XCD 4
    // consecutive row panels; within an XCD, sweep columns first so all its
    // resident blocks share one G panel.
    const int bid = blockIdx.x;              // 0..2047
    const int xcd = bid & 7;
    const int l   = bid >> 3;                // 0..255
    const int rowBase = (xcd * 4 + (l >> 6)) * 128;   // over NG
    const int colBase = (l & 63) * 128;               // over NCOL

    // B staging: 128 rows x 64 k; row stride 128B; 16B chunks; XOR swizzle
    // LDS slot (r, cp) holds global chunk c = cp ^ (r&7)
    const unsigned short* Bptr[4];
    int ldsOff[4];
#pragma unroll
    for (int i = 0; i < 4; ++i) {
        const int s  = i * 256 + tid;
        const int r  = s >> 3;
        const int cp = s & 7;
        const int c  = cp ^ (r & 7);
        Bptr[i] = F + (size_t)(colBase + r) * KDIM + c * 8;
        ldsOff[i] = s * 8;
    }

    // A fragment pointers: row = rowBase + waveM*64 + i*16 + m, chunk quad*8
    const unsigned short* Aptr[4];
#pragma unroll
    for (int i = 0; i < 4; ++i)
        Aptr[i] = G + (size_t)(rowBase + waveM * 64 + i * 16 + m) * KDIM + quad * 8;

    f32x4 acc[4][4];
#pragma unroll
    for (int i = 0; i < 4; ++i)
#pragma unroll
        for (int j = 0; j < 4; ++j)
            acc[i][j] = (f32x4){0.f, 0.f, 0.f, 0.f};

    for (int k0 = 0; k0 < KDIM; k0 += 64) {
        // A fragments for this iter: 8 direct b128 loads (L2-hot G panel)
        bf16x8 a[2][4];
#pragma unroll
        for (int h = 0; h < 2; ++h)
#pragma unroll
            for (int i = 0; i < 4; ++i)
                a[h][i] = *(const bf16x8*)(Aptr[i] + k0 + h * 32);

#pragma unroll
        for (int i = 0; i < 4; ++i) async16(Bptr[i] + k0, &ldsB[ldsOff[i]]);
        __syncthreads();

#pragma unroll
        for (int h = 0; h < 2; ++h) {
            bf16x8 b[4];
#pragma unroll
            for (int j = 0; j < 4; ++j) {
                const int r  = waveN * 64 + j * 16 + m;
                const int cp = (h * 4 + quad) ^ (r & 7);
                b[j] = *(const bf16x8*)&ldsB[r * 64 + cp * 8];
            }
#pragma unroll
            for (int i = 0; i < 4; ++i)
#pragma unroll
                for (int j = 0; j < 4; ++j)
                    acc[i][j] = __builtin_amdgcn_mfma_f32_16x16x32_bf16(a[h][i], b[j], acc[i][j], 0, 0, 0);
        }
        __syncthreads();
    }

    // Epilogue: out[b][n] += sum_c pooled[n][b*256+c] * weight[n][c]
    const int bidx  = colBase >> 8;
    const int cwave = (colBase & 255) + waveN * 64;   // + j*16 + m
#pragma unroll
    for (int i = 0; i < 4; ++i) {
        const int nrow = rowBase + waveM * 64 + i * 16 + quad * 4;  // + reg
#pragma unroll
        for (int reg = 0; reg < 4; ++reg) {
            const float* wrow = weight + (size_t)(nrow + reg) * 256 + cwave + m;
            float s = acc[i][0][reg] * wrow[0]
                    + acc[i][1][reg] * wrow[16]
                    + acc[i][2][reg] * wrow[32]
                    + acc[i][3][reg] * wrow[48];
            s += __shfl_xor(s, 1);
            s += __shfl_xor(s, 2);
            s += __shfl_xor(s, 4);
            s += __shfl_xor(s, 8);
            if (m == 0)
                atomicAdd(out + (size_t)bidx * NG + nrow + reg, s);
        }
    }
}

// ---------------------------------------------------------------------------
extern "C" void kernel_launch(void* const* d_in, const int* in_sizes, int n_in,
                              void* d_out, int out_size, void* d_ws, size_t ws_size,
                              hipStream_t stream) {
    const float* feat   = (const float*)d_in[0];
    const float* mu     = (const float*)d_in[1];
    const float* logsx  = (const float*)d_in[2];
    const float* logsy  = (const float*)d_in[3];
    const float* rho    = (const float*)d_in[4];
    const float* weight = (const float*)d_in[5];
    float* out = (float*)d_out;

    unsigned short* Gbuf = (unsigned short*)d_ws;                  // 4096*2304*2 B
    unsigned short* Fbuf = Gbuf + (size_t)NG * P_HW;               // 8192*2304*2 B

    hipLaunchKernelGGL(prep_kernel, dim3(13376), dim3(256), 0, stream,
                       feat, mu, logsx, logsy, rho, Fbuf, Gbuf, out);

    hipLaunchKernelGGL(gemm_fused, dim3(2048), dim3(256), 0, stream,
                       Gbuf, Fbuf, weight, out);
}

// Round 6
// 302.987 us; speedup vs baseline: 1.5655x; 1.5655x over previous
//
#include <hip/hip_runtime.h>
#include <hip/hip_bf16.h>

// B=32, C=256, H=36, W=64, n=4096.  P = H*W = 2304.  NCOL = B*C = 8192.
#define P_HW   2304
#define NG     4096
#define NCOL   8192
#define KDIM   P_HW

typedef __bf16 bf16x8 __attribute__((ext_vector_type(8)));
typedef float  f32x4  __attribute__((ext_vector_type(4)));

__device__ __forceinline__ unsigned short f2bf(float f) {
    union { float f; unsigned int u; } x; x.f = f;
    unsigned int r = x.u + 0x7FFFu + ((x.u >> 16) & 1u);   // RNE
    return (unsigned short)(r >> 16);
}

// ---------------------------------------------------------------------------
// Fused prep: [0,9216) cast feat->bf16 | [9216,13312) gaussian masks |
//             [13312,13376) zero out.  One dispatch, all independent.
// ---------------------------------------------------------------------------
__global__ __launch_bounds__(256) void prep_kernel(
    const float* __restrict__ feat,
    const float* __restrict__ mu,
    const float* __restrict__ logsx,
    const float* __restrict__ logsy,
    const float* __restrict__ rho,
    unsigned short* __restrict__ F,
    unsigned short* __restrict__ G,
    float* __restrict__ out) {
    const int bid = blockIdx.x;
    const int tid = threadIdx.x;
    if (bid < 9216) {
        // cast feat fp32 -> bf16, [B*C][P], 8 elems/thread
        const size_t i = ((size_t)bid * 256 + tid) * 8;
        const float4 v0 = *(const float4*)(feat + i);
        const float4 v1 = *(const float4*)(feat + i + 4);
        union { unsigned short s[8]; uint4 q; } o;
        o.s[0] = f2bf(v0.x); o.s[1] = f2bf(v0.y); o.s[2] = f2bf(v0.z); o.s[3] = f2bf(v0.w);
        o.s[4] = f2bf(v1.x); o.s[5] = f2bf(v1.y); o.s[6] = f2bf(v1.z); o.s[7] = f2bf(v1.w);
        *(uint4*)(F + i) = o.q;
    } else if (bid < 13312) {
        const int n = bid - 9216;
        const float mux = mu[2 * n], muy = mu[2 * n + 1];
        const float sx = __expf(logsx[n]) + 1e-6f;
        const float sy = __expf(logsy[n]) + 1e-6f;
        const float r  = tanhf(rho[n]);
        const float inv_den = 1.0f / (2.0f * (1.0f - r * r + 1e-6f));
        const float isx = 1.0f / sx, isy = 1.0f / sy;
        for (int base = tid * 8; base < P_HW; base += 2048) {
            const int h = base >> 6, w0 = base & 63;      // W = 64
            const float Y  = -1.0f + (float)h * (2.0f / 35.0f);
            const float yc = (Y - muy) * isy;
            union { unsigned short s[8]; uint4 q; } o;
#pragma unroll
            for (int j = 0; j < 8; ++j) {
                const float X  = -1.0f + (float)(w0 + j) * (2.0f / 63.0f);
                const float xc = (X - mux) * isx;
                const float A  = xc * xc + yc * yc - 2.0f * r * xc * yc;
                o.s[j] = f2bf(__expf(-A * inv_den));
            }
            *(uint4*)&G[(size_t)n * P_HW + base] = o.q;
        }
    } else {
        // zero out: 64 blocks * 256 threads * 8 floats = 131072 = 32*4096
        const size_t i = ((size_t)(bid - 13312) * 256 + tid) * 8;
        const float4 z = {0.f, 0.f, 0.f, 0.f};
        *(float4*)(out + i)     = z;
        *(float4*)(out + i + 4) = z;
    }
}

// ---------------------------------------------------------------------------
// GEMM: 128x128 tile, BK=64, XOR-swizzled LDS (conflict-free for the 16x16
// fragment pattern), global_load_lds(16B) staging for BOTH A and B (R5 lesson:
// direct-global fragments put L2 latency on the MFMA critical path — never
// again), 16x16x32 bf16 MFMA, fused weight-dot epilogue.
// XCD-affinity swizzle: xcd = bid&7 pinned to F panel group x = xcd*8+phase,
// y sweeps fastest -> concurrent same-XCD blocks share one F panel in L2.
// ---------------------------------------------------------------------------
__device__ __forceinline__ void async16(const void* g, void* l) {
    __builtin_amdgcn_global_load_lds(
        (__attribute__((address_space(1))) void*)(unsigned long long)g,
        (__attribute__((address_space(3))) void*)(unsigned int)(unsigned long long)l,
        16, 0, 0);
}

__global__ __launch_bounds__(256) void gemm_fused(
    const unsigned short* __restrict__ G,   // [NG][K] bf16
    const unsigned short* __restrict__ F,   // [NCOL][K] bf16
    const float* __restrict__ weight,       // [NG][256] fp32
    float* __restrict__ out)                // [32][NG] fp32 (pre-zeroed)
{
    // 128 rows x 64 k per tile; row stride 128B; chunk = 16B (8 bf16)
    // LDS slot (r, cp) holds global chunk c = cp ^ (r&7)  [XOR swizzle]
    __shared__ __align__(16) unsigned short ldsA[128 * 64];
    __shared__ __align__(16) unsigned short ldsB[128 * 64];

    const int tid  = threadIdx.x;
    const int lane = tid & 63;
    const int wave = tid >> 6;
    const int waveM = wave >> 1, waveN = wave & 1;
    const int quad = lane >> 4, m = lane & 15;

    // XCD-affinity swizzle: 2048 blocks; xcd=bid&7 -> x in [8*xcd, 8*xcd+8),
    // y fastest. Concurrent blocks on one XCD share ~1-2 F panels (L2-hot).
    const int bid = blockIdx.x;
    const int xcd = bid & 7;
    const int idx = bid >> 3;                 // 0..255
    const int xcol = xcd * 8 + (idx >> 5);    // 0..63
    const int yrow = idx & 31;                // 0..31

    const int rowBase = yrow * 128;   // over NG
    const int colBase = xcol * 128;   // over NCOL (b*256+c)

    // staging: 1024 slots of 16B per tile -> 4 issues/thread per tile
    const unsigned short* Aptr[4];
    const unsigned short* Bptr[4];
    int ldsOff[4];
#pragma unroll
    for (int i = 0; i < 4; ++i) {
        const int s  = i * 256 + tid;
        const int r  = s >> 3;
        const int cp = s & 7;
        const int c  = cp ^ (r & 7);           // swizzled source chunk
        Aptr[i] = G + (size_t)(rowBase + r) * KDIM + c * 8;
        Bptr[i] = F + (size_t)(colBase + r) * KDIM + c * 8;
        ldsOff[i] = s * 8;                     // elems
    }

    f32x4 acc[4][4];
#pragma unroll
    for (int i = 0; i < 4; ++i)
#pragma unroll
        for (int j = 0; j < 4; ++j)
            acc[i][j] = (f32x4){0.f, 0.f, 0.f, 0.f};

    for (int k0 = 0; k0 < KDIM; k0 += 64) {
#pragma unroll
        for (int i = 0; i < 4; ++i) async16(Aptr[i] + k0, &ldsA[ldsOff[i]]);
#pragma unroll
        for (int i = 0; i < 4; ++i) async16(Bptr[i] + k0, &ldsB[ldsOff[i]]);
        __syncthreads();

#pragma unroll
        for (int h = 0; h < 2; ++h) {
            bf16x8 a[4], b[4];
#pragma unroll
            for (int i = 0; i < 4; ++i) {
                const int r  = waveM * 64 + i * 16 + m;
                const int cp = (h * 4 + quad) ^ (r & 7);
                a[i] = *(const bf16x8*)&ldsA[r * 64 + cp * 8];
            }
#pragma unroll
            for (int j = 0; j < 4; ++j) {
                const int r  = waveN * 64 + j * 16 + m;
                const int cp = (h * 4 + quad) ^ (r & 7);
                b[j] = *(const bf16x8*)&ldsB[r * 64 + cp * 8];
            }
#pragma unroll
            for (int i = 0; i < 4; ++i)
#pragma unroll
                for (int j = 0; j < 4; ++j)
                    acc[i][j] = __builtin_amdgcn_mfma_f32_16x16x32_bf16(a[i], b[j], acc[i][j], 0, 0, 0);
        }
        __syncthreads();
    }

    // Epilogue: out[b][n] += sum_c pooled[n][b*256+c] * weight[n][c]
    const int bidx  = colBase >> 8;
    const int cwave = (colBase & 255) + waveN * 64;   // + j*16 + m
#pragma unroll
    for (int i = 0; i < 4; ++i) {
        const int nrow = rowBase + waveM * 64 + i * 16 + quad * 4;  // + reg
#pragma unroll
        for (int reg = 0; reg < 4; ++reg) {
            const float* wrow = weight + (size_t)(nrow + reg) * 256 + cwave + m;
            float s = acc[i][0][reg] * wrow[0]
                    + acc[i][1][reg] * wrow[16]
                    + acc[i][2][reg] * wrow[32]
                    + acc[i][3][reg] * wrow[48];
            s += __shfl_xor(s, 1);
            s += __shfl_xor(s, 2);
            s += __shfl_xor(s, 4);
            s += __shfl_xor(s, 8);
            if (m == 0)
                atomicAdd(out + (size_t)bidx * NG + nrow + reg, s);
        }
    }
}

// ---------------------------------------------------------------------------
extern "C" void kernel_launch(void* const* d_in, const int* in_sizes, int n_in,
                              void* d_out, int out_size, void* d_ws, size_t ws_size,
                              hipStream_t stream) {
    const float* feat   = (const float*)d_in[0];
    const float* mu     = (const float*)d_in[1];
    const float* logsx  = (const float*)d_in[2];
    const float* logsy  = (const float*)d_in[3];
    const float* rho    = (const float*)d_in[4];
    const float* weight = (const float*)d_in[5];
    float* out = (float*)d_out;

    unsigned short* Gbuf = (unsigned short*)d_ws;                  // 4096*2304*2 B
    unsigned short* Fbuf = Gbuf + (size_t)NG * P_HW;               // 8192*2304*2 B

    hipLaunchKernelGGL(prep_kernel, dim3(13376), dim3(256), 0, stream,
                       feat, mu, logsx, logsy, rho, Fbuf, Gbuf, out);

    hipLaunchKernelGGL(gemm_fused, dim3(2048), dim3(256), 0, stream,
                       Gbuf, Fbuf, weight, out);
}

// Round 7
// 275.629 us; speedup vs baseline: 1.7208x; 1.0993x over previous
//
#include <hip/hip_runtime.h>
#include <hip/hip_bf16.h>

// B=32, C=256, H=36, W=64, n=4096.  P = H*W = 2304.  NCOL = B*C = 8192.
#define P_HW   2304
#define NG     4096
#define NCOL   8192
#define KDIM   P_HW

typedef __bf16 bf16x8 __attribute__((ext_vector_type(8)));
typedef float  f32x4  __attribute__((ext_vector_type(4)));

__device__ __forceinline__ unsigned short f2bf(float f) {
    union { float f; unsigned int u; } x; x.f = f;
    unsigned int r = x.u + 0x7FFFu + ((x.u >> 16) & 1u);   // RNE
    return (unsigned short)(r >> 16);
}

// ---------------------------------------------------------------------------
// Fused prep: [0,9216) cast feat->bf16 | [9216,13312) gaussian masks |
//             [13312,13376) zero out.  One dispatch, all independent.
// ---------------------------------------------------------------------------
__global__ __launch_bounds__(256) void prep_kernel(
    const float* __restrict__ feat,
    const float* __restrict__ mu,
    const float* __restrict__ logsx,
    const float* __restrict__ logsy,
    const float* __restrict__ rho,
    unsigned short* __restrict__ F,
    unsigned short* __restrict__ G,
    float* __restrict__ out) {
    const int bid = blockIdx.x;
    const int tid = threadIdx.x;
    if (bid < 9216) {
        // cast feat fp32 -> bf16, [B*C][P], 8 elems/thread
        const size_t i = ((size_t)bid * 256 + tid) * 8;
        const float4 v0 = *(const float4*)(feat + i);
        const float4 v1 = *(const float4*)(feat + i + 4);
        union { unsigned short s[8]; uint4 q; } o;
        o.s[0] = f2bf(v0.x); o.s[1] = f2bf(v0.y); o.s[2] = f2bf(v0.z); o.s[3] = f2bf(v0.w);
        o.s[4] = f2bf(v1.x); o.s[5] = f2bf(v1.y); o.s[6] = f2bf(v1.z); o.s[7] = f2bf(v1.w);
        *(uint4*)(F + i) = o.q;
    } else if (bid < 13312) {
        const int n = bid - 9216;
        const float mux = mu[2 * n], muy = mu[2 * n + 1];
        const float sx = __expf(logsx[n]) + 1e-6f;
        const float sy = __expf(logsy[n]) + 1e-6f;
        const float r  = tanhf(rho[n]);
        const float inv_den = 1.0f / (2.0f * (1.0f - r * r + 1e-6f));
        const float isx = 1.0f / sx, isy = 1.0f / sy;
        for (int base = tid * 8; base < P_HW; base += 2048) {
            const int h = base >> 6, w0 = base & 63;      // W = 64
            const float Y  = -1.0f + (float)h * (2.0f / 35.0f);
            const float yc = (Y - muy) * isy;
            union { unsigned short s[8]; uint4 q; } o;
#pragma unroll
            for (int j = 0; j < 8; ++j) {
                const float X  = -1.0f + (float)(w0 + j) * (2.0f / 63.0f);
                const float xc = (X - mux) * isx;
                const float A  = xc * xc + yc * yc - 2.0f * r * xc * yc;
                o.s[j] = f2bf(__expf(-A * inv_den));
            }
            *(uint4*)&G[(size_t)n * P_HW + base] = o.q;
        }
    } else {
        // zero out: 64 blocks * 256 threads * 8 floats = 131072 = 32*4096
        const size_t i = ((size_t)(bid - 13312) * 256 + tid) * 8;
        const float4 z = {0.f, 0.f, 0.f, 0.f};
        *(float4*)(out + i)     = z;
        *(float4*)(out + i + 4) = z;
    }
}

// ---------------------------------------------------------------------------
// GEMM: 128x128 block tile, BK=64, 2 waves (128 thr), wave tile 64x128 with
// acc 4x8 -> 12 ds_read_b128 per 32 MFMA (was 8:16) — cuts the binding LDS
// read pipe 25%. XOR-swizzled LDS (conflict-free), global_load_lds(16B)
// staging for BOTH A and B (R5 lesson: keep L2 off the MFMA critical path).
// Plain 2D grid (R6 lesson: XCD column-affinity swizzle doubled FETCH).
// ---------------------------------------------------------------------------
__device__ __forceinline__ void async16(const void* g, void* l) {
    __builtin_amdgcn_global_load_lds(
        (__attribute__((address_space(1))) void*)(unsigned long long)g,
        (__attribute__((address_space(3))) void*)(unsigned int)(unsigned long long)l,
        16, 0, 0);
}

__global__ __launch_bounds__(128, 2) void gemm_fused(
    const unsigned short* __restrict__ G,   // [NG][K] bf16
    const unsigned short* __restrict__ F,   // [NCOL][K] bf16
    const float* __restrict__ weight,       // [NG][256] fp32
    float* __restrict__ out)                // [32][NG] fp32 (pre-zeroed)
{
    // 128 rows x 64 k per tile; row stride 128B; chunk = 16B (8 bf16)
    // LDS slot (r, cp) holds global chunk c = cp ^ (r&7)  [XOR swizzle]
    __shared__ __align__(16) unsigned short ldsA[128 * 64];
    __shared__ __align__(16) unsigned short ldsB[128 * 64];

    const int tid  = threadIdx.x;            // 0..127
    const int lane = tid & 63;
    const int wave = tid >> 6;               // 0,1 -> rows [wave*64, +64)
    const int quad = lane >> 4, m = lane & 15;

    const int rowBase = blockIdx.y * 128;    // over NG
    const int colBase = blockIdx.x * 128;    // over NCOL (b*256+c)

    // staging: 1024 slots of 16B per array; slot s = i*128 + tid, i = 0..7.
    // r = s>>3 steps by 16 as i increments -> (r&7) and hence the swizzled
    // chunk c are i-invariant; ptr offset per i is the constant 16*KDIM elems.
    const int r0 = tid >> 3;
    const int c0 = (tid & 7) ^ (r0 & 7);
    const unsigned short* Aptr0 = G + (size_t)(rowBase + r0) * KDIM + c0 * 8;
    const unsigned short* Bptr0 = F + (size_t)(colBase + r0) * KDIM + c0 * 8;
    const int lds0 = tid * 8;                // + i*1024 elems

    f32x4 acc[4][8];
#pragma unroll
    for (int i = 0; i < 4; ++i)
#pragma unroll
        for (int j = 0; j < 8; ++j)
            acc[i][j] = (f32x4){0.f, 0.f, 0.f, 0.f};

    for (int k0 = 0; k0 < KDIM; k0 += 64) {
#pragma unroll
        for (int i = 0; i < 8; ++i)
            async16(Aptr0 + k0 + i * 16 * KDIM, &ldsA[lds0 + i * 1024]);
#pragma unroll
        for (int i = 0; i < 8; ++i)
            async16(Bptr0 + k0 + i * 16 * KDIM, &ldsB[lds0 + i * 1024]);
        __syncthreads();

#pragma unroll
        for (int h = 0; h < 2; ++h) {
            bf16x8 a[4], b[8];
#pragma unroll
            for (int i = 0; i < 4; ++i) {
                const int r  = wave * 64 + i * 16 + m;
                const int cp = (h * 4 + quad) ^ (r & 7);
                a[i] = *(const bf16x8*)&ldsA[r * 64 + cp * 8];
            }
#pragma unroll
            for (int j = 0; j < 8; ++j) {
                const int r  = j * 16 + m;
                const int cp = (h * 4 + quad) ^ (r & 7);
                b[j] = *(const bf16x8*)&ldsB[r * 64 + cp * 8];
            }
#pragma unroll
            for (int i = 0; i < 4; ++i)
#pragma unroll
                for (int j = 0; j < 8; ++j)
                    acc[i][j] = __builtin_amdgcn_mfma_f32_16x16x32_bf16(a[i], b[j], acc[i][j], 0, 0, 0);
        }
        __syncthreads();
    }

    // Epilogue: out[b][n] += sum_c pooled[n][b*256+c] * weight[n][c]
    // acc[i][j][reg] = pooled[rowBase + wave*64 + i*16 + quad*4 + reg]
    //                        [colBase + j*16 + m]
    const int bidx   = colBase >> 8;
    const int cwbase = (colBase & 255) + m;
#pragma unroll
    for (int i = 0; i < 4; ++i) {
#pragma unroll
        for (int reg = 0; reg < 4; ++reg) {
            const int n = rowBase + wave * 64 + i * 16 + quad * 4 + reg;
            const float* wrow = weight + (size_t)n * 256 + cwbase;
            float s = 0.f;
#pragma unroll
            for (int j = 0; j < 8; ++j)
                s += acc[i][j][reg] * wrow[j * 16];
            // reduce over the 16 m-lanes of this quad (same n, different cols)
            s += __shfl_xor(s, 1);
            s += __shfl_xor(s, 2);
            s += __shfl_xor(s, 4);
            s += __shfl_xor(s, 8);
            if (m == 0)
                atomicAdd(out + (size_t)bidx * NG + n, s);
        }
    }
}

// ---------------------------------------------------------------------------
extern "C" void kernel_launch(void* const* d_in, const int* in_sizes, int n_in,
                              void* d_out, int out_size, void* d_ws, size_t ws_size,
                              hipStream_t stream) {
    const float* feat   = (const float*)d_in[0];
    const float* mu     = (const float*)d_in[1];
    const float* logsx  = (const float*)d_in[2];
    const float* logsy  = (const float*)d_in[3];
    const float* rho    = (const float*)d_in[4];
    const float* weight = (const float*)d_in[5];
    float* out = (float*)d_out;

    unsigned short* Gbuf = (unsigned short*)d_ws;                  // 4096*2304*2 B
    unsigned short* Fbuf = Gbuf + (size_t)NG * P_HW;               // 8192*2304*2 B

    hipLaunchKernelGGL(prep_kernel, dim3(13376), dim3(256), 0, stream,
                       feat, mu, logsx, logsy, rho, Fbuf, Gbuf, out);

    hipLaunchKernelGGL(gemm_fused, dim3(NCOL / 128, NG / 128), dim3(128), 0, stream,
                       Gbuf, Fbuf, weight, out);
}